// Round 3
// baseline (3528.380 us; speedup 1.0000x reference)
//
#include <hip/hip_runtime.h>
#include <math.h>

// K-means m=100000, n=128, K=128, 15 iters, tol=1e-4 — bit-exact f32 replication
// of the numpy/jax reference arithmetic:
//  - dots: sequential in-order FMA chain over d (BLAS microkernel order)
//  - x_sq/c_sq/norm: numpy pairwise-8 pattern (8 strided accumulators + fixed tree)
//  - d2 = (x_sq - 2*dot) + c_sq, each op individually rounded (__f*_rn)
//  - argmin: first-min-wins
//  - segment sums: sequential f32 adds in ascending point order (stable sort)
// Outputs (f32): centroids [128*128], clusters [100000] (ids as floats).

#define KC 128
#define ND 128

__device__ __forceinline__ unsigned mapf(float s) {
    unsigned b = __float_as_uint(s);
    return (b & 0x80000000u) ? ~b : (b | 0x80000000u);  // order-preserving f32->u32
}

__device__ __forceinline__ bool is_done(const int* __restrict__ conv, int t) {
    bool d = false;
    for (int j = 0; j < t; ++j) d |= (conv[j] == KC);
    return d;
}

// numpy pairwise-8 combine tree
__device__ __forceinline__ float comb8(const float* r) {
    float t1 = __fadd_rn(__fadd_rn(r[0], r[1]), __fadd_rn(r[2], r[3]));
    float t2 = __fadd_rn(__fadd_rn(r[4], r[5]), __fadd_rn(r[6], r[7]));
    return __fadd_rn(t1, t2);
}

// ---- x_sq per point (once): numpy pairwise-8 over rounded squares ----
__global__ __launch_bounds__(256) void xsq_k(const float* __restrict__ X,
                                             float* __restrict__ xsq, int m) {
    int p = blockIdx.x * 256 + threadIdx.x;
    if (p >= m) return;
    const float* xr = X + (size_t)p * ND;
    float r[8];
#pragma unroll
    for (int j = 0; j < 8; ++j) r[j] = __fmul_rn(xr[j], xr[j]);
    for (int b = 1; b < 16; ++b) {
#pragma unroll
        for (int j = 0; j < 8; ++j) {
            float v = xr[8 * b + j];
            r[j] = __fadd_rn(r[j], __fmul_rn(v, v));
        }
    }
    xsq[p] = comb8(r);
}

// ---- csq of initial centroids: one thread per k, same pattern ----
__global__ __launch_bounds__(128) void csq0_k(const float* __restrict__ c,
                                              float* __restrict__ csq) {
    int k = threadIdx.x;
    const float* cr = c + k * ND;
    float r[8];
#pragma unroll
    for (int j = 0; j < 8; ++j) r[j] = __fmul_rn(cr[j], cr[j]);
    for (int b = 1; b < 16; ++b) {
#pragma unroll
        for (int j = 0; j < 8; ++j) {
            float v = cr[8 * b + j];
            r[j] = __fadd_rn(r[j], __fmul_rn(v, v));
        }
    }
    csq[k] = comb8(r);
}

// ---- assign: grid ceil(m/128), block 256; 4 points x 8 clusters per thread ----
__global__ __launch_bounds__(256) void assign_k(
    const float* __restrict__ X, const float* __restrict__ cent,
    const float* __restrict__ csq, const float* __restrict__ xsq,
    int* __restrict__ cl, float* __restrict__ cl_out,
    const int* __restrict__ conv, int t, int m)
{
    if (is_done(conv, t)) return;
    __shared__ float Cl[64 * ND];     // 32 KB: half the centroids
    __shared__ float csql[128];
    __shared__ unsigned long long mk[128];

    const int tid = threadIdx.x;
    const int ptg = tid & 31, kg = tid >> 5;
    const int base = blockIdx.x * 128;

    if (tid < 128) { mk[tid] = ~0ULL; csql[tid] = csq[tid]; }

    int pts[4];
    const float4* xrow[4];
    float xq[4];
#pragma unroll
    for (int i = 0; i < 4; ++i) {
        int pt = base + ptg + 32 * i;
        pts[i] = pt;
        int safe = pt < m ? pt : (m - 1);
        xrow[i] = (const float4*)(X + (size_t)safe * ND);
        xq[i] = xsq[safe];
    }

    float best[4];
    int bk[4] = {0, 0, 0, 0};
#pragma unroll
    for (int i = 0; i < 4; ++i) best[i] = __int_as_float(0x7f800000);

#pragma unroll 1
    for (int h = 0; h < 2; ++h) {
        __syncthreads();
        const float4* ch = (const float4*)(cent + h * 64 * ND);
#pragma unroll
        for (int q = 0; q < 8; ++q) {
            int f = tid + 256 * q;              // 2048 float4 = 64x128 floats
            ((float4*)Cl)[f] = ch[f];
        }
        __syncthreads();

        float acc[4][8];
#pragma unroll
        for (int i = 0; i < 4; ++i)
#pragma unroll
            for (int j = 0; j < 8; ++j) acc[i][j] = 0.0f;

        const float4* crow[8];
#pragma unroll
        for (int j = 0; j < 8; ++j) crow[j] = (const float4*)(Cl + (kg * 8 + j) * ND);

#pragma unroll 4
        for (int dc = 0; dc < 32; ++dc) {        // d = 4*dc .. 4*dc+3, ascending
            float4 a[4];
#pragma unroll
            for (int i = 0; i < 4; ++i) a[i] = xrow[i][dc];
            float4 b[8];
#pragma unroll
            for (int j = 0; j < 8; ++j) b[j] = crow[j][dc];
#pragma unroll
            for (int i = 0; i < 4; ++i)
#pragma unroll
                for (int j = 0; j < 8; ++j) {
                    float s = acc[i][j];
                    s = __fmaf_rn(a[i].x, b[j].x, s);
                    s = __fmaf_rn(a[i].y, b[j].y, s);
                    s = __fmaf_rn(a[i].z, b[j].z, s);
                    s = __fmaf_rn(a[i].w, b[j].w, s);
                    acc[i][j] = s;
                }
        }

#pragma unroll
        for (int j = 0; j < 8; ++j) {           // ascending k for first-min-wins
            int kk = h * 64 + kg * 8 + j;
            float cs = csql[kk];
#pragma unroll
            for (int i = 0; i < 4; ++i) {
                // (x_sq - 2*dot) + c_sq, each op rounded
                float d2 = __fadd_rn(__fsub_rn(xq[i], __fmul_rn(2.0f, acc[i][j])), cs);
                if (d2 < best[i]) { best[i] = d2; bk[i] = kk; }
            }
        }
    }

#pragma unroll
    for (int i = 0; i < 4; ++i)
        if (pts[i] < m) {
            unsigned long long key =
                ((unsigned long long)mapf(best[i]) << 32) | (unsigned)bk[i];
            atomicMin(&mk[ptg + 32 * i], key);
        }
    __syncthreads();
    if (tid < 128) {
        int pt = base + tid;
        if (pt < m) {
            int k = (int)(mk[tid] & 0xFFFFFFFFu);
            cl[pt] = k;
            cl_out[pt] = (float)k;
        }
    }
}

// ---- hist + stable in-chunk rank (chunk = 64 consecutive points = 1 wave) ----
__global__ __launch_bounds__(256) void hist_k(
    const int* __restrict__ cl, unsigned char* __restrict__ rankA,
    unsigned char* __restrict__ hist, const int* __restrict__ conv,
    int t, int m, int nch)
{
    if (is_done(conv, t)) return;
    const int tid = threadIdx.x;
    const int wave = tid >> 6, lane = tid & 63;
    const int chunk = blockIdx.x * 4 + wave;
    if (chunk >= nch) return;
    const int p = chunk * 64 + lane;
    const int cli = (p < m) ? cl[p] : -1;
    int rank = 0, cnt = 0;
    for (int b = 0; b < 64; ++b) {
        int cb = __shfl(cli, b);
        if (cb == cli) { cnt++; if (b < lane) rank++; }
    }
    if (p < m) {
        rankA[p] = (unsigned char)rank;
        hist[(size_t)cli * nch + chunk] = (unsigned char)cnt;
    }
}

// ---- per-cluster prefix over chunks: block k, 256 threads ----
__global__ __launch_bounds__(256) void scan_k(
    const unsigned char* __restrict__ hist, unsigned* __restrict__ cbase,
    int* __restrict__ counts, const int* __restrict__ conv, int t, int nch)
{
    if (is_done(conv, t)) return;
    const int k = blockIdx.x, tid = threadIdx.x;
    const int strip = (nch + 255) >> 8;
    __shared__ int ss[256];
    int s = 0;
    for (int j = 0; j < strip; ++j) {
        int c = tid * strip + j;
        if (c < nch) s += hist[(size_t)k * nch + c];
    }
    ss[tid] = s;
    __syncthreads();
    if (tid == 0) {
        int run = 0;
        for (int i = 0; i < 256; ++i) { int v = ss[i]; ss[i] = run; run += v; }
        counts[k] = run;
    }
    __syncthreads();
    int run = ss[tid];
    for (int j = 0; j < strip; ++j) {
        int c = tid * strip + j;
        if (c < nch) {
            cbase[(size_t)k * nch + c] = (unsigned)run;
            run += hist[(size_t)k * nch + c];
        }
    }
}

// ---- exclusive scan over clusters ----
__global__ __launch_bounds__(64) void off_k(
    const int* __restrict__ counts, int* __restrict__ off,
    const int* __restrict__ conv, int t)
{
    if (is_done(conv, t)) return;
    if (threadIdx.x == 0) {
        int run = 0;
        for (int k = 0; k < KC; ++k) { off[k] = run; run += counts[k]; }
        off[KC] = run;
    }
}

// ---- scatter point ids into stable per-cluster lists ----
__global__ __launch_bounds__(256) void scatter_k(
    const int* __restrict__ cl, const unsigned char* __restrict__ rankA,
    const unsigned* __restrict__ cbase, const int* __restrict__ off,
    unsigned* __restrict__ plist, const int* __restrict__ conv,
    int t, int m, int nch)
{
    if (is_done(conv, t)) return;
    int p = blockIdx.x * 256 + threadIdx.x;
    if (p >= m) return;
    int c = cl[p];
    int chunk = p >> 6;
    plist[off[c] + cbase[(size_t)c * nch + chunk] + rankA[p]] = (unsigned)p;
}

__device__ __forceinline__ void loadb16(float* dst, int basei, int n,
                                        const unsigned* __restrict__ pl,
                                        const float* __restrict__ X, int d) {
#pragma unroll
    for (int j = 0; j < 16; ++j) {
        int idx = basei + j;
        int sidx = idx < n ? idx : n - 1;
        float v = X[(size_t)pl[sidx] * ND + d];
        dst[j] = idx < n ? v : 0.0f;   // +0.0f is exact identity for fadd
    }
}

// ---- segment mean in ascending point order + csq + convergence ----
__global__ __launch_bounds__(128) void update_k(
    const float* __restrict__ X, const unsigned* __restrict__ plist,
    const int* __restrict__ off, const int* __restrict__ counts,
    const float* __restrict__ cent_old, float* __restrict__ cent_new,
    float* __restrict__ csq_new, int* __restrict__ conv, int t)
{
    if (is_done(conv, t)) return;
    const int k = blockIdx.x, d = threadIdx.x;
    const int n = counts[k];
    float s = 0.0f;
    if (n > 0) {
        const unsigned* pl = plist + off[k];
        float A[16], B[16], C_[16];
        loadb16(A, 0, n, pl, X, d);
        loadb16(B, 16, n, pl, X, d);
        for (int basei = 0; basei < n; basei += 16) {
            loadb16(C_, basei + 32, n, pl, X, d);
#pragma unroll
            for (int j = 0; j < 16; ++j) s = __fadd_rn(s, A[j]);
#pragma unroll
            for (int j = 0; j < 16; ++j) { A[j] = B[j]; B[j] = C_[j]; }
        }
    }
    const float old = cent_old[k * ND + d];
    const float nv = (n > 0) ? __fdiv_rn(s, (float)n) : old;
    cent_new[k * ND + d] = nv;

    __shared__ float sv[128], dv[128], rr[8], dd[8];
    sv[d] = nv;
    dv[d] = __fsub_rn(nv, old);
    __syncthreads();
    if (d < 8) {
        float r = __fmul_rn(sv[d], sv[d]);
        float q = __fmul_rn(dv[d], dv[d]);
        for (int b = 1; b < 16; ++b) {
            float c1 = sv[8 * b + d], c2 = dv[8 * b + d];
            r = __fadd_rn(r, __fmul_rn(c1, c1));
            q = __fadd_rn(q, __fmul_rn(c2, c2));
        }
        rr[d] = r; dd[d] = q;
    }
    __syncthreads();
    if (d == 0) {
        csq_new[k] = comb8(rr);
        float ns = comb8(dd);
        if (__fsqrt_rn(ns) < 1e-4f) atomicAdd(&conv[t], 1);
    }
}

// ---- final: pick the right centroid buffer ----
__global__ __launch_bounds__(256) void final_k(
    const float* __restrict__ cent_bufs, const int* __restrict__ conv,
    float* __restrict__ out)
{
    int tf = 15;
    for (int j = 14; j >= 0; --j)
        if (conv[j] == KC) tf = j;
    const float* c = cent_bufs + (size_t)(tf & 1) * KC * ND;
    int i = blockIdx.x * 256 + threadIdx.x;
    out[i] = c[i];
}

extern "C" void kernel_launch(void* const* d_in, const int* in_sizes, int n_in,
                              void* d_out, int out_size, void* d_ws, size_t ws_size,
                              hipStream_t stream) {
    const float* X = (const float*)d_in[0];
    const float* cent0 = (const float*)d_in[1];
    float* outF = (float*)d_out;
    const int m = in_sizes[0] / ND;      // 100000
    const int nch = (m + 63) / 64;       // 1563

    unsigned char* w = (unsigned char*)d_ws;
    float* centb = (float*)w;            w += (size_t)2 * KC * ND * 4;
    float* csqb = (float*)w;             w += (size_t)2 * KC * 4;
    float* xsq = (float*)w;              w += (size_t)m * 4;
    int* cl = (int*)w;                   w += (size_t)m * 4;
    unsigned* plist = (unsigned*)w;      w += (size_t)m * 4;
    unsigned* cbase = (unsigned*)w;      w += (size_t)KC * nch * 4;
    int* off = (int*)w;                  w += 132 * 4;
    int* counts = (int*)w;               w += KC * 4;
    int* conv = (int*)w;                 w += 16 * 4;
    unsigned char* rankA = w;            w += (size_t)m;
    unsigned char* hist = w;             w += (size_t)KC * nch;

    hipMemsetAsync(conv, 0, 16 * sizeof(int), stream);
    hipMemcpyAsync(centb, cent0, KC * ND * sizeof(float),
                   hipMemcpyDeviceToDevice, stream);
    csq0_k<<<1, 128, 0, stream>>>(centb, csqb);

    const int gp = (m + 255) / 256;          // 391
    const int gh = (nch + 3) / 4;            // 391
    const int ga = (m + 127) / 128;          // 782
    xsq_k<<<gp, 256, 0, stream>>>(X, xsq, m);

    for (int t = 0; t < 15; ++t) {
        const float* cc = centb + (size_t)(t & 1) * KC * ND;
        float* cn = centb + (size_t)((t + 1) & 1) * KC * ND;
        const float* cs = csqb + (t & 1) * KC;
        float* csn = csqb + ((t + 1) & 1) * KC;

        assign_k<<<ga, 256, 0, stream>>>(X, cc, cs, xsq, cl, outF + KC * ND,
                                         conv, t, m);
        hipMemsetAsync(hist, 0, (size_t)KC * nch, stream);
        hist_k<<<gh, 256, 0, stream>>>(cl, rankA, hist, conv, t, m, nch);
        scan_k<<<KC, 256, 0, stream>>>(hist, cbase, counts, conv, t, nch);
        off_k<<<1, 64, 0, stream>>>(counts, off, conv, t);
        scatter_k<<<gp, 256, 0, stream>>>(cl, rankA, cbase, off, plist,
                                          conv, t, m, nch);
        update_k<<<KC, 128, 0, stream>>>(X, plist, off, counts, cc, cn, csn,
                                         conv, t);
    }
    final_k<<<KC * ND / 256, 256, 0, stream>>>(centb, conv, outF);
}

// Round 4
// 2979.775 us; speedup vs baseline: 1.1841x; 1.1841x over previous
//
#include <hip/hip_runtime.h>
#include <math.h>

// K-means m=100000, n=128, K=128, 15 iters, tol=1e-4 — bit-exact f32 replication
// of the numpy/jax reference arithmetic:
//  - dots: sequential in-order FMA chain over d (BLAS microkernel order)
//  - x_sq/c_sq/norm: numpy pairwise-8 pattern (8 strided accumulators + fixed tree)
//  - d2 = (x_sq - 2*dot) + c_sq, each op individually rounded (__f*_rn)
//  - argmin: first-min-wins
//  - segment sums: sequential f32 adds in ascending point order (stable sort)
// R4: materialize cluster-sorted X (sortx_k) so the order-mandated serial sums
// in update2_k stream contiguously instead of gathering (was 476us latency-bound,
// VGPR=32 scratch spills). Add order/values unchanged -> still bit-exact.
// Outputs (f32): centroids [128*128], clusters [100000] (ids as floats).

#define KC 128
#define ND 128

__device__ __forceinline__ unsigned mapf(float s) {
    unsigned b = __float_as_uint(s);
    return (b & 0x80000000u) ? ~b : (b | 0x80000000u);  // order-preserving f32->u32
}

__device__ __forceinline__ bool is_done(const int* __restrict__ conv, int t) {
    bool d = false;
    for (int j = 0; j < t; ++j) d |= (conv[j] == KC);
    return d;
}

// numpy pairwise-8 combine tree
__device__ __forceinline__ float comb8(const float* r) {
    float t1 = __fadd_rn(__fadd_rn(r[0], r[1]), __fadd_rn(r[2], r[3]));
    float t2 = __fadd_rn(__fadd_rn(r[4], r[5]), __fadd_rn(r[6], r[7]));
    return __fadd_rn(t1, t2);
}

// ---- x_sq per point (once): numpy pairwise-8 over rounded squares ----
__global__ __launch_bounds__(256) void xsq_k(const float* __restrict__ X,
                                             float* __restrict__ xsq, int m) {
    int p = blockIdx.x * 256 + threadIdx.x;
    if (p >= m) return;
    const float* xr = X + (size_t)p * ND;
    float r[8];
#pragma unroll
    for (int j = 0; j < 8; ++j) r[j] = __fmul_rn(xr[j], xr[j]);
    for (int b = 1; b < 16; ++b) {
#pragma unroll
        for (int j = 0; j < 8; ++j) {
            float v = xr[8 * b + j];
            r[j] = __fadd_rn(r[j], __fmul_rn(v, v));
        }
    }
    xsq[p] = comb8(r);
}

// ---- csq of initial centroids: one thread per k, same pattern ----
__global__ __launch_bounds__(128) void csq0_k(const float* __restrict__ c,
                                              float* __restrict__ csq) {
    int k = threadIdx.x;
    const float* cr = c + k * ND;
    float r[8];
#pragma unroll
    for (int j = 0; j < 8; ++j) r[j] = __fmul_rn(cr[j], cr[j]);
    for (int b = 1; b < 16; ++b) {
#pragma unroll
        for (int j = 0; j < 8; ++j) {
            float v = cr[8 * b + j];
            r[j] = __fadd_rn(r[j], __fmul_rn(v, v));
        }
    }
    csq[k] = comb8(r);
}

// ---- assign: grid ceil(m/128), block 256; 4 points x 8 clusters per thread ----
__global__ __launch_bounds__(256) void assign_k(
    const float* __restrict__ X, const float* __restrict__ cent,
    const float* __restrict__ csq, const float* __restrict__ xsq,
    int* __restrict__ cl, float* __restrict__ cl_out,
    const int* __restrict__ conv, int t, int m)
{
    if (is_done(conv, t)) return;
    __shared__ float Cl[64 * ND];     // 32 KB: half the centroids
    __shared__ float csql[128];
    __shared__ unsigned long long mk[128];

    const int tid = threadIdx.x;
    const int ptg = tid & 31, kg = tid >> 5;
    const int base = blockIdx.x * 128;

    if (tid < 128) { mk[tid] = ~0ULL; csql[tid] = csq[tid]; }

    int pts[4];
    const float4* xrow[4];
    float xq[4];
#pragma unroll
    for (int i = 0; i < 4; ++i) {
        int pt = base + ptg + 32 * i;
        pts[i] = pt;
        int safe = pt < m ? pt : (m - 1);
        xrow[i] = (const float4*)(X + (size_t)safe * ND);
        xq[i] = xsq[safe];
    }

    float best[4];
    int bk[4] = {0, 0, 0, 0};
#pragma unroll
    for (int i = 0; i < 4; ++i) best[i] = __int_as_float(0x7f800000);

#pragma unroll 1
    for (int h = 0; h < 2; ++h) {
        __syncthreads();
        const float4* ch = (const float4*)(cent + h * 64 * ND);
#pragma unroll
        for (int q = 0; q < 8; ++q) {
            int f = tid + 256 * q;              // 2048 float4 = 64x128 floats
            ((float4*)Cl)[f] = ch[f];
        }
        __syncthreads();

        float acc[4][8];
#pragma unroll
        for (int i = 0; i < 4; ++i)
#pragma unroll
            for (int j = 0; j < 8; ++j) acc[i][j] = 0.0f;

        const float4* crow[8];
#pragma unroll
        for (int j = 0; j < 8; ++j) crow[j] = (const float4*)(Cl + (kg * 8 + j) * ND);

#pragma unroll 4
        for (int dc = 0; dc < 32; ++dc) {        // d = 4*dc .. 4*dc+3, ascending
            float4 a[4];
#pragma unroll
            for (int i = 0; i < 4; ++i) a[i] = xrow[i][dc];
            float4 b[8];
#pragma unroll
            for (int j = 0; j < 8; ++j) b[j] = crow[j][dc];
#pragma unroll
            for (int i = 0; i < 4; ++i)
#pragma unroll
                for (int j = 0; j < 8; ++j) {
                    float s = acc[i][j];
                    s = __fmaf_rn(a[i].x, b[j].x, s);
                    s = __fmaf_rn(a[i].y, b[j].y, s);
                    s = __fmaf_rn(a[i].z, b[j].z, s);
                    s = __fmaf_rn(a[i].w, b[j].w, s);
                    acc[i][j] = s;
                }
        }

#pragma unroll
        for (int j = 0; j < 8; ++j) {           // ascending k for first-min-wins
            int kk = h * 64 + kg * 8 + j;
            float cs = csql[kk];
#pragma unroll
            for (int i = 0; i < 4; ++i) {
                // (x_sq - 2*dot) + c_sq, each op rounded
                float d2 = __fadd_rn(__fsub_rn(xq[i], __fmul_rn(2.0f, acc[i][j])), cs);
                if (d2 < best[i]) { best[i] = d2; bk[i] = kk; }
            }
        }
    }

#pragma unroll
    for (int i = 0; i < 4; ++i)
        if (pts[i] < m) {
            unsigned long long key =
                ((unsigned long long)mapf(best[i]) << 32) | (unsigned)bk[i];
            atomicMin(&mk[ptg + 32 * i], key);
        }
    __syncthreads();
    if (tid < 128) {
        int pt = base + tid;
        if (pt < m) {
            int k = (int)(mk[tid] & 0xFFFFFFFFu);
            cl[pt] = k;
            cl_out[pt] = (float)k;
        }
    }
}

// ---- hist + stable in-chunk rank (chunk = 64 consecutive points = 1 wave) ----
__global__ __launch_bounds__(256) void hist_k(
    const int* __restrict__ cl, unsigned char* __restrict__ rankA,
    unsigned char* __restrict__ hist, const int* __restrict__ conv,
    int t, int m, int nch)
{
    if (is_done(conv, t)) return;
    const int tid = threadIdx.x;
    const int wave = tid >> 6, lane = tid & 63;
    const int chunk = blockIdx.x * 4 + wave;
    if (chunk >= nch) return;
    const int p = chunk * 64 + lane;
    const int cli = (p < m) ? cl[p] : -1;
    int rank = 0, cnt = 0;
    for (int b = 0; b < 64; ++b) {
        int cb = __shfl(cli, b);
        if (cb == cli) { cnt++; if (b < lane) rank++; }
    }
    if (p < m) {
        rankA[p] = (unsigned char)rank;
        hist[(size_t)cli * nch + chunk] = (unsigned char)cnt;
    }
}

// ---- per-cluster prefix over chunks: block k, 256 threads ----
__global__ __launch_bounds__(256) void scan_k(
    const unsigned char* __restrict__ hist, unsigned* __restrict__ cbase,
    int* __restrict__ counts, const int* __restrict__ conv, int t, int nch)
{
    if (is_done(conv, t)) return;
    const int k = blockIdx.x, tid = threadIdx.x;
    const int strip = (nch + 255) >> 8;
    __shared__ int ss[256];
    int s = 0;
    for (int j = 0; j < strip; ++j) {
        int c = tid * strip + j;
        if (c < nch) s += hist[(size_t)k * nch + c];
    }
    ss[tid] = s;
    __syncthreads();
    if (tid == 0) {
        int run = 0;
        for (int i = 0; i < 256; ++i) { int v = ss[i]; ss[i] = run; run += v; }
        counts[k] = run;
    }
    __syncthreads();
    int run = ss[tid];
    for (int j = 0; j < strip; ++j) {
        int c = tid * strip + j;
        if (c < nch) {
            cbase[(size_t)k * nch + c] = (unsigned)run;
            run += hist[(size_t)k * nch + c];
        }
    }
}

// ---- exclusive scan over clusters ----
__global__ __launch_bounds__(64) void off_k(
    const int* __restrict__ counts, int* __restrict__ off,
    const int* __restrict__ conv, int t)
{
    if (is_done(conv, t)) return;
    if (threadIdx.x == 0) {
        int run = 0;
        for (int k = 0; k < KC; ++k) { off[k] = run; run += counts[k]; }
        off[KC] = run;
    }
}

// ---- scatter point ids into stable per-cluster lists ----
__global__ __launch_bounds__(256) void scatter_k(
    const int* __restrict__ cl, const unsigned char* __restrict__ rankA,
    const unsigned* __restrict__ cbase, const int* __restrict__ off,
    unsigned* __restrict__ plist, const int* __restrict__ conv,
    int t, int m, int nch)
{
    if (is_done(conv, t)) return;
    int p = blockIdx.x * 256 + threadIdx.x;
    if (p >= m) return;
    int c = cl[p];
    int chunk = p >> 6;
    plist[off[c] + cbase[(size_t)c * nch + chunk] + rankA[p]] = (unsigned)p;
}

// ---- materialize cluster-sorted X: Xs[s] = X[plist[s]] (coalesced both sides) ----
__global__ __launch_bounds__(256) void sortx_k(
    const float* __restrict__ X, const unsigned* __restrict__ plist,
    float* __restrict__ Xs, const int* __restrict__ conv, int t, int m)
{
    if (is_done(conv, t)) return;
    const int s = blockIdx.x * 8 + (threadIdx.x >> 5);
    if (s >= m) return;
    const int q = threadIdx.x & 31;
    const float4 v = ((const float4*)(X + (size_t)plist[s] * ND))[q];
    ((float4*)(Xs + (size_t)s * ND))[q] = v;
}

// ---- shared epilogue of the update kernels ----
__device__ __forceinline__ void update_epi(
    int k, int d, int n, float s,
    const float* __restrict__ cent_old, float* __restrict__ cent_new,
    float* __restrict__ csq_new, int* __restrict__ conv, int t)
{
    const float old = cent_old[k * ND + d];
    const float nv = (n > 0) ? __fdiv_rn(s, (float)n) : old;
    cent_new[k * ND + d] = nv;

    __shared__ float sv[128], dv[128], rr[8], dd[8];
    sv[d] = nv;
    dv[d] = __fsub_rn(nv, old);
    __syncthreads();
    if (d < 8) {
        float r = __fmul_rn(sv[d], sv[d]);
        float q = __fmul_rn(dv[d], dv[d]);
        for (int b = 1; b < 16; ++b) {
            float c1 = sv[8 * b + d], c2 = dv[8 * b + d];
            r = __fadd_rn(r, __fmul_rn(c1, c1));
            q = __fadd_rn(q, __fmul_rn(c2, c2));
        }
        rr[d] = r; dd[d] = q;
    }
    __syncthreads();
    if (d == 0) {
        csq_new[k] = comb8(rr);
        float ns = comb8(dd);
        if (__fsqrt_rn(ns) < 1e-4f) atomicAdd(&conv[t], 1);
    }
}

// ---- segment mean from sorted X: streaming, 32-deep load batches ----
__global__ __launch_bounds__(128) void update2_k(
    const float* __restrict__ Xs, const int* __restrict__ off,
    const int* __restrict__ counts, const float* __restrict__ cent_old,
    float* __restrict__ cent_new, float* __restrict__ csq_new,
    int* __restrict__ conv, int t)
{
    if (is_done(conv, t)) return;
    const int k = blockIdx.x, d = threadIdx.x;
    const int n = counts[k];
    float s = 0.0f;
    if (n > 0) {
        const float* col = Xs + (size_t)off[k] * ND + d;
#pragma unroll 1
        for (int i0 = 0; i0 < n; i0 += 32) {
            float v[32];
#pragma unroll
            for (int j = 0; j < 32; ++j) {       // 32 independent loads in flight
                int idx = i0 + j;
                int sidx = idx < n ? idx : 0;
                float x = col[(size_t)sidx * ND];
                v[j] = idx < n ? x : 0.0f;       // +0.0f exact identity for fadd
            }
#pragma unroll
            for (int j = 0; j < 32; ++j) s = __fadd_rn(s, v[j]);  // mandated order
        }
    }
    update_epi(k, d, n, s, cent_old, cent_new, csq_new, conv, t);
}

// ---- fallback (small ws): gather-based segment mean (R3 version) ----
__global__ __launch_bounds__(128) void update_k(
    const float* __restrict__ X, const unsigned* __restrict__ plist,
    const int* __restrict__ off, const int* __restrict__ counts,
    const float* __restrict__ cent_old, float* __restrict__ cent_new,
    float* __restrict__ csq_new, int* __restrict__ conv, int t)
{
    if (is_done(conv, t)) return;
    const int k = blockIdx.x, d = threadIdx.x;
    const int n = counts[k];
    float s = 0.0f;
    if (n > 0) {
        const unsigned* pl = plist + off[k];
#pragma unroll 1
        for (int i0 = 0; i0 < n; i0 += 32) {
            float v[32];
#pragma unroll
            for (int j = 0; j < 32; ++j) {
                int idx = i0 + j;
                int sidx = idx < n ? idx : 0;
                float x = X[(size_t)pl[sidx] * ND + d];
                v[j] = idx < n ? x : 0.0f;
            }
#pragma unroll
            for (int j = 0; j < 32; ++j) s = __fadd_rn(s, v[j]);
        }
    }
    update_epi(k, d, n, s, cent_old, cent_new, csq_new, conv, t);
}

// ---- final: pick the right centroid buffer ----
__global__ __launch_bounds__(256) void final_k(
    const float* __restrict__ cent_bufs, const int* __restrict__ conv,
    float* __restrict__ out)
{
    int tf = 15;
    for (int j = 14; j >= 0; --j)
        if (conv[j] == KC) tf = j;
    const float* c = cent_bufs + (size_t)(tf & 1) * KC * ND;
    int i = blockIdx.x * 256 + threadIdx.x;
    out[i] = c[i];
}

extern "C" void kernel_launch(void* const* d_in, const int* in_sizes, int n_in,
                              void* d_out, int out_size, void* d_ws, size_t ws_size,
                              hipStream_t stream) {
    const float* X = (const float*)d_in[0];
    const float* cent0 = (const float*)d_in[1];
    float* outF = (float*)d_out;
    const int m = in_sizes[0] / ND;      // 100000
    const int nch = (m + 63) / 64;       // 1563

    unsigned char* w = (unsigned char*)d_ws;
    float* centb = (float*)w;            w += (size_t)2 * KC * ND * 4;
    float* csqb = (float*)w;             w += (size_t)2 * KC * 4;
    float* xsq = (float*)w;              w += (size_t)m * 4;
    int* cl = (int*)w;                   w += (size_t)m * 4;
    unsigned* plist = (unsigned*)w;      w += (size_t)m * 4;
    unsigned* cbase = (unsigned*)w;      w += (size_t)KC * nch * 4;
    int* off = (int*)w;                  w += 132 * 4;
    int* counts = (int*)w;               w += KC * 4;
    int* conv = (int*)w;                 w += 16 * 4;
    unsigned char* rankA = w;            w += (size_t)m;
    unsigned char* hist = w;             w += (size_t)KC * nch;
    // 16B-align Xs, appended last so the fallback layout is unchanged
    w = (unsigned char*)(((uintptr_t)w + 15) & ~(uintptr_t)15);
    float* Xs = (float*)w;
    const bool use_sorted =
        ((unsigned char*)Xs - (unsigned char*)d_ws) + (size_t)m * ND * 4 <= ws_size;

    hipMemsetAsync(conv, 0, 16 * sizeof(int), stream);
    hipMemcpyAsync(centb, cent0, KC * ND * sizeof(float),
                   hipMemcpyDeviceToDevice, stream);
    csq0_k<<<1, 128, 0, stream>>>(centb, csqb);

    const int gp = (m + 255) / 256;          // 391
    const int gh = (nch + 3) / 4;            // 391
    const int ga = (m + 127) / 128;          // 782
    const int gs = (m + 7) / 8;              // 12500
    xsq_k<<<gp, 256, 0, stream>>>(X, xsq, m);

    for (int t = 0; t < 15; ++t) {
        const float* cc = centb + (size_t)(t & 1) * KC * ND;
        float* cn = centb + (size_t)((t + 1) & 1) * KC * ND;
        const float* cs = csqb + (t & 1) * KC;
        float* csn = csqb + ((t + 1) & 1) * KC;

        assign_k<<<ga, 256, 0, stream>>>(X, cc, cs, xsq, cl, outF + KC * ND,
                                         conv, t, m);
        hipMemsetAsync(hist, 0, (size_t)KC * nch, stream);
        hist_k<<<gh, 256, 0, stream>>>(cl, rankA, hist, conv, t, m, nch);
        scan_k<<<KC, 256, 0, stream>>>(hist, cbase, counts, conv, t, nch);
        off_k<<<1, 64, 0, stream>>>(counts, off, conv, t);
        scatter_k<<<gp, 256, 0, stream>>>(cl, rankA, cbase, off, plist,
                                          conv, t, m, nch);
        if (use_sorted) {
            sortx_k<<<gs, 256, 0, stream>>>(X, plist, Xs, conv, t, m);
            update2_k<<<KC, 128, 0, stream>>>(Xs, off, counts, cc, cn, csn,
                                              conv, t);
        } else {
            update_k<<<KC, 128, 0, stream>>>(X, plist, off, counts, cc, cn, csn,
                                             conv, t);
        }
    }
    final_k<<<KC * ND / 256, 256, 0, stream>>>(centb, conv, outF);
}